// Round 1
// 785.175 us; speedup vs baseline: 1.1802x; 1.1802x over previous
//
#include <hip/hip_runtime.h>
#include <math.h>

// ComplexPolarTransformerBeta — round 9: algebraic QK fusion.
// scores = scale*(M Wq)(M Wk)^T  ==  scale*M (Wq Wk^T) M^T  + rank-1 terms.
// Terms constant along softmax axis cancel; surviving term v_j = M_j (scale*Wk bq)
// is a cheap register reduction. prep0 computes W' = Wq Wk^T (fp32, LDS-staged,
// conflict-free 129-stride) + u = scale*Wk*bq; pack kernel frag-packs W' like Wq.
// Per layer this removes: 1 of 7 GEMMs, 2 of 8 stageB64 passes (mag stays
// resident in R1 across T/S/Vm GEMMs), and the 12-barrier Pf quarter-buffer —
// bias now builds once in R2 as a full 64KB fp32 matrix (transposed Bf[j][i] so
// reads are 2-way-free), since R2 is dead at layer start. Barriers ~25 -> 14.
// LDS: 2x69632 + 2x2048 = 143360 B (still 1 block/CU).

typedef __attribute__((ext_vector_type(8)))  short s16x8;
typedef __attribute__((ext_vector_type(16))) float f32x16;

#define STR  136      // LDS row stride (shorts): 128 data + 8 pad
#define LOFS 17408    // lo-plane offset within a region (shorts)
#define MFMA(a, b, c) __builtin_amdgcn_mfma_f32_32x32x16_bf16(a, b, c, 0, 0, 0)
#define ROWP(reg) (((reg) & 3) + (((reg) >> 2) << 3) + (h5 << 2))

__device__ __forceinline__ unsigned short bfhi(float x) {
  unsigned u = __float_as_uint(x);
  return (unsigned short)((u + 0x7FFFu + ((u >> 16) & 1u)) >> 16);
}
__device__ __forceinline__ float bf2f(unsigned short h) {
  return __uint_as_float(((unsigned)h) << 16);
}

// Stage one C-layout tile into S[row][colbase + 8q + 4h5] as bf16 hi/lo (b64).
__device__ __forceinline__ void stageB64(short* SH, const f32x16& acc, int row,
                                         int colbase, int h5, float scl) {
  #pragma unroll
  for (int q = 0; q < 4; ++q) {
    int col = colbase + 8 * q + 4 * h5;
    float v0 = acc[4*q+0] * scl, v1 = acc[4*q+1] * scl;
    float v2 = acc[4*q+2] * scl, v3 = acc[4*q+3] * scl;
    unsigned short h0 = bfhi(v0), h1 = bfhi(v1), h2 = bfhi(v2), h3 = bfhi(v3);
    *(short4*)(SH + row * STR + col) = make_short4((short)h0,(short)h1,(short)h2,(short)h3);
    *(short4*)(SH + LOFS + row * STR + col) =
        make_short4((short)bfhi(v0 - bf2f(h0)), (short)bfhi(v1 - bf2f(h1)),
                    (short)bfhi(v2 - bf2f(h2)), (short)bfhi(v3 - bf2f(h3)));
  }
}

// acc[tt] += Wfrag(m-tile)^ * B(LDS rows 32tt+l31).  D[m=frag][n=LDS-row]
__device__ __forceinline__ void gemmTW4(f32x16* acc, const short* W, const short* BH,
                                        int mtile, int kbN, int l31, int h5, int lane) {
  #pragma unroll 1
  for (int kb = 0; kb < kbN; ++kb) {
    const short* wp = W + (((mtile * 8 + kb) * 64 + lane) * 8);
    s16x8 ah = *(const s16x8*)wp;
    s16x8 al = *(const s16x8*)(wp + 32768);
    int k0 = kb * 16 + 8 * h5;
    #pragma unroll
    for (int tt = 0; tt < 4; ++tt) {
      int brow = 32 * tt + l31;
      s16x8 bh = *(const s16x8*)(BH + brow * STR + k0);
      s16x8 bl = *(const s16x8*)(BH + LOFS + brow * STR + k0);
      acc[tt] = MFMA(ah, bh, acc[tt]);
      acc[tt] = MFMA(ah, bl, acc[tt]);
      acc[tt] = MFMA(al, bh, acc[tt]);
    }
  }
}

// acc[tt] += A(LDS rows mblk+l31) * Wfrag(n-tile=tt).  D[m=LDS-row][n=frag]
__device__ __forceinline__ void gemmNW4(f32x16* acc, const short* AH, const short* W,
                                        int mblk, int l31, int h5, int lane) {
  int arow = mblk + l31;
  #pragma unroll 1
  for (int kb = 0; kb < 8; ++kb) {
    int k0 = kb * 16 + 8 * h5;
    s16x8 ah = *(const s16x8*)(AH + arow * STR + k0);
    s16x8 al = *(const s16x8*)(AH + LOFS + arow * STR + k0);
    #pragma unroll
    for (int tt = 0; tt < 4; ++tt) {
      const short* wp = W + (((tt * 8 + kb) * 64 + lane) * 8);
      s16x8 bh = *(const s16x8*)wp;
      s16x8 bl = *(const s16x8*)(wp + 32768);
      acc[tt] = MFMA(ah, bh, acc[tt]);
      acc[tt] = MFMA(ah, bl, acc[tt]);
      acc[tt] = MFMA(al, bh, acc[tt]);
    }
  }
}

// acc[tt] += A(LDS rows mblk+l31) * B(LDS rows 32tt+l31)^T.
__device__ __forceinline__ void gemmLL4(f32x16* acc, const short* AH, const short* BH,
                                        int mblk, int l31, int h5) {
  int arow = mblk + l31;
  #pragma unroll 1
  for (int kb = 0; kb < 8; ++kb) {
    int k0 = kb * 16 + 8 * h5;
    s16x8 ah = *(const s16x8*)(AH + arow * STR + k0);
    s16x8 al = *(const s16x8*)(AH + LOFS + arow * STR + k0);
    #pragma unroll
    for (int tt = 0; tt < 4; ++tt) {
      int brow = 32 * tt + l31;
      s16x8 bh = *(const s16x8*)(BH + brow * STR + k0);
      s16x8 bl = *(const s16x8*)(BH + LOFS + brow * STR + k0);
      acc[tt] = MFMA(ah, bh, acc[tt]);
      acc[tt] = MFMA(ah, bl, acc[tt]);
      acc[tt] = MFMA(al, bh, acc[tt]);
    }
  }
}

// ---------------- prep0: W'[l] = Wq[l] @ Wk[l]^T (fp32), u[l] = scale*Wk[l]@bq[l] ----
__global__ __launch_bounds__(256)
void prep0_kernel(const float* __restrict__ Wq, const float* __restrict__ Wk,
                  const float* __restrict__ bq,
                  float* __restrict__ wprime, float* __restrict__ u) {
  __shared__ float WkS[128 * 129];
  __shared__ float WqS[32 * 129];
  int l = blockIdx.x >> 2, ablk = blockIdx.x & 3;
  int t = threadIdx.x;
  const float* wk = Wk + (size_t)l * 16384;
  const float* wq = Wq + (size_t)l * 16384 + ablk * 32 * 128;
  for (int idx = t; idx < 16384; idx += 256)
    WkS[(idx >> 7) * 129 + (idx & 127)] = wk[idx];
  for (int idx = t; idx < 4096; idx += 256)
    WqS[(idx >> 7) * 129 + (idx & 127)] = wq[idx];
  __syncthreads();
  int a = t >> 3, bs = t & 7;
  float acc[16];
  #pragma unroll
  for (int j = 0; j < 16; ++j) acc[j] = 0.f;
  for (int c = 0; c < 128; ++c) {
    float qa = WqS[a * 129 + c];
    #pragma unroll
    for (int j = 0; j < 16; ++j) acc[j] += qa * WkS[(8 * j + bs) * 129 + c];
  }
  float* dst = wprime + ((size_t)l * 128 + ablk * 32 + a) * 128;
  #pragma unroll
  for (int j = 0; j < 16; ++j) dst[8 * j + bs] = acc[j];
  if (ablk == 0 && t < 128) {
    float s = 0.f;
    const float* bql = bq + l * 128;
    for (int c = 0; c < 128; ++c) s += WkS[t * 129 + c] * bql[c];
    u[l * 128 + t] = 0.08838834764831845f * s;
  }
}

// ---------------- weight packing: fp32 [k][h] -> frag-ordered bf16 hi/lo ----------
// mids: 0-3 W', 4-7 Wvm, 8-11 Wvp, 12-13 rp_W halves, 14-15 emb.
__global__ __launch_bounds__(512)
void prep_kernel(const float* __restrict__ wprime,
                 const float* __restrict__ Wvm, const float* __restrict__ Wvp,
                 const float* __restrict__ rp_W,
                 const float* __restrict__ emb_Wm, const float* __restrict__ emb_Wp,
                 short* __restrict__ ws) {
  int mid = blockIdx.x >> 2, hblk = blockIdx.x & 3;
  int kb = threadIdx.x >> 6, lane = threadIdx.x & 63;
  const float* src;
  int krows = 128;
  if (mid < 4)        src = wprime + (size_t)mid * 16384;
  else if (mid < 8)   src = Wvm + (size_t)(mid - 4) * 16384;
  else if (mid < 12)  src = Wvp + (size_t)(mid - 8) * 16384;
  else if (mid == 12) src = rp_W;
  else if (mid == 13) src = rp_W + 16384;
  else if (mid == 14) { src = emb_Wm; krows = 19; }
  else                { src = emb_Wp; krows = 19; }
  int h = hblk * 32 + (lane & 31);
  int kbase = kb * 16 + ((lane >> 5) << 3);
  s16x8 H, L;
  #pragma unroll
  for (int j = 0; j < 8; ++j) {
    int k = kbase + j;
    float v = (k < krows) ? src[(size_t)k * 128 + h] : 0.f;
    unsigned short hi = bfhi(v);
    H[j] = (short)hi;
    L[j] = (short)bfhi(v - bf2f(hi));
  }
  short* dst = ws + (size_t)mid * 65536 + ((hblk * 8 + kb) * 64 + lane) * 8;
  *(s16x8*)dst = H;
  *(s16x8*)(dst + 32768) = L;
}

// ---------------- main kernel ----------------
__global__ __launch_bounds__(256, 2)
void cpt_kernel(const float* __restrict__ atom_types,
                const float* __restrict__ coords,
                const int*   __restrict__ edge_index,
                const float* __restrict__ edge_attr,
                const float* __restrict__ emb_bm, const float* __restrict__ emb_bp,
                const float* __restrict__ bvm, const float* __restrict__ bvp,
                const float* __restrict__ We,  const float* __restrict__ be,
                const float* __restrict__ dist_scale,
                const float* __restrict__ ln_g, const float* __restrict__ ln_b,
                const float* __restrict__ rp_b,
                const float* __restrict__ h1_W, const float* __restrict__ h1_b,
                const float* __restrict__ h2_W, const float* __restrict__ h2_b,
                const short* __restrict__ wpre, const float* __restrict__ uArr,
                float* __restrict__ out)
{
  __shared__ __align__(16) short R1s[34816];
  __shared__ __align__(16) short R2s[34816];
  __shared__ float SCa[512];
  __shared__ float SCb[512];

  const int t = threadIdx.x, b = blockIdx.x;
  const int w = t >> 6, lane = t & 63, l31 = lane & 31, h5 = lane >> 5;
  const int mblk = w << 5;
  const float scale = 0.08838834764831845f;  // 1/sqrt(128)

  // ---- stage x (atom_types||coords, k padded to 32) into R1 as bf16 hi/lo ----
  if (t < 128) {
    const float* xr = atom_types + ((size_t)b * 128 + t) * 16;
    const float* cr = coords + ((size_t)b * 128 + t) * 3;
    float xv[19];
    float4 a0 = *(const float4*)xr,       a1 = *(const float4*)(xr + 4);
    float4 a2 = *(const float4*)(xr + 8), a3 = *(const float4*)(xr + 12);
    xv[0]=a0.x; xv[1]=a0.y; xv[2]=a0.z; xv[3]=a0.w;
    xv[4]=a1.x; xv[5]=a1.y; xv[6]=a1.z; xv[7]=a1.w;
    xv[8]=a2.x; xv[9]=a2.y; xv[10]=a2.z; xv[11]=a2.w;
    xv[12]=a3.x; xv[13]=a3.y; xv[14]=a3.z; xv[15]=a3.w;
    xv[16]=cr[0]; xv[17]=cr[1]; xv[18]=cr[2];
    #pragma unroll
    for (int k = 0; k < 32; ++k) {
      float v = (k < 19) ? xv[k] : 0.f;
      unsigned short hh = bfhi(v);
      R1s[t * STR + k] = (short)hh;
      R1s[LOFS + t * STR + k] = (short)bfhi(v - bf2f(hh));
    }
  }
  __syncthreads();

  // ---- embedding via MFMA: magT/phT (TRANSPOSED: h=32w+ROWP(reg), a=32tt+l31) ----
  f32x16 magT[4], phT[4];
  {
    #pragma unroll
    for (int reg = 0; reg < 16; ++reg) {
      float bm = emb_bm[32 * w + ROWP(reg)];
      float bp = emb_bp[32 * w + ROWP(reg)];
      #pragma unroll
      for (int tt = 0; tt < 4; ++tt) { magT[tt][reg] = bm; phT[tt][reg] = bp; }
    }
    gemmTW4(magT, wpre + (size_t)14 * 65536, R1s, w, 2, l31, h5, lane);
    gemmTW4(phT,  wpre + (size_t)15 * 65536, R1s, w, 2, l31, h5, lane);
  }

  // ---- layers ----
  for (int l = 0; l < 4; ++l) {
    const short* wpP  = wpre + (size_t)l * 65536;        // W' pack
    const short* wvmP = wpre + (size_t)(4 + l) * 65536;
    const short* wvpP = wpre + (size_t)(8 + l) * 65536;
    float* Bf = (float*)R2s;                             // 128x128 bias, [j][i]

    __syncthreads();                                 // prior layer readers done
    #pragma unroll
    for (int tt = 0; tt < 4; ++tt)
      stageB64(R1s, magT[tt], 32 * tt + l31, mblk, h5, 1.f);   // mag[a][h] -> R1
    {
      float4 z4 = make_float4(0.f, 0.f, 0.f, 0.f);
      #pragma unroll
      for (int k = 0; k < 16; ++k) *(float4*)(Bf + (t + 256 * k) * 4) = z4;
    }
    // v partials: v_a = sum_h mag[a][h] * u[h]  (this wave's 32-h block)
    {
      float ur[16];
      #pragma unroll
      for (int reg = 0; reg < 16; ++reg) ur[reg] = uArr[l * 128 + 32 * w + ROWP(reg)];
      #pragma unroll
      for (int tt = 0; tt < 4; ++tt) {
        float p = 0.f;
        #pragma unroll
        for (int reg = 0; reg < 16; ++reg) p += magT[tt][reg] * ur[reg];
        p += __shfl_xor(p, 32);
        if (h5 == 0) SCa[w * 128 + 32 * tt + l31] = p;
      }
    }
    __syncthreads();                                 // mag/Bf-zero/v ready

    // edge bias scatter: Bf[j][i] += bval
    {
      float w0 = We[l*4], w1 = We[l*4+1], w2 = We[l*4+2], w3 = We[l*4+3];
      float bel = be[l], dsl = dist_scale[l];
      #pragma unroll
      for (int k = 0; k < 4; ++k) {
        int e = t + 256 * k;
        int e0 = edge_index[(size_t)b * 2048 + e];
        int e1 = edge_index[(size_t)b * 2048 + 1024 + e];
        float4 ea = *(const float4*)(edge_attr + ((size_t)b * 1024 + e) * 4);
        float bv = ea.x*w0 + ea.y*w1 + ea.z*w2 + ea.w*w3 + bel + dsl*ea.x;
        atomicAdd(&Bf[e1 * 128 + e0], bv);
      }
    }

    // T = mag @ W'  (accT: m=b'=32w+ROWP, n=i=32tt+l31); mag stays in R1
    f32x16 accT[4];
    #pragma unroll
    for (int tt = 0; tt < 4; ++tt)
      #pragma unroll
      for (int reg = 0; reg < 16; ++reg) accT[tt][reg] = 0.f;
    gemmTW4(accT, wpP, R1s, w, 8, l31, h5, lane);
    __syncthreads();                                 // atomics visible

    // accS init = bias[i][j] + v_j  (m=j=32w+ROWP, n=i=32tt+l31)
    f32x16 accS[4];
    {
      float vj[16];
      #pragma unroll
      for (int reg = 0; reg < 16; ++reg) {
        int j = 32 * w + ROWP(reg);
        vj[reg] = SCa[j] + SCa[128 + j] + SCa[256 + j] + SCa[384 + j];
      }
      #pragma unroll
      for (int tt = 0; tt < 4; ++tt) {
        #pragma unroll
        for (int reg = 0; reg < 16; ++reg)
          accS[tt][reg] = Bf[(32 * w + ROWP(reg)) * 128 + 32 * tt + l31] + vj[reg];
      }
    }
    __syncthreads();                                 // Bf reads done
    #pragma unroll
    for (int tt = 0; tt < 4; ++tt)
      stageB64(R2s, accT[tt], 32 * tt + l31, mblk, h5, scale);  // Ts[i][b'] -> R2
    __syncthreads();                                 // Ts ready

    // scoresT[j][i] = mag @ Ts^T + bias + v
    gemmLL4(accS, R1s, R2s, mblk, l31, h5);

    // softmax over j (regs + h5 partner + 4 waves via SCa/SCb)
    #pragma unroll
    for (int tt = 0; tt < 4; ++tt) {
      float m = accS[tt][0];
      #pragma unroll
      for (int reg = 1; reg < 16; ++reg) m = fmaxf(m, accS[tt][reg]);
      m = fmaxf(m, __shfl_xor(m, 32));
      if (h5 == 0) SCa[w * 128 + 32 * tt + l31] = m;
    }
    __syncthreads();
    #pragma unroll
    for (int tt = 0; tt < 4; ++tt) {
      int i = 32 * tt + l31;
      float mg = fmaxf(fmaxf(SCa[i], SCa[128 + i]), fmaxf(SCa[256 + i], SCa[384 + i]));
      float s = 0.f;
      #pragma unroll
      for (int reg = 0; reg < 16; ++reg) {
        float e = __expf(accS[tt][reg] - mg);
        accS[tt][reg] = e; s += e;
      }
      s += __shfl_xor(s, 32);
      if (h5 == 0) SCb[w * 128 + i] = s;
    }
    __syncthreads();
    #pragma unroll
    for (int tt = 0; tt < 4; ++tt) {
      int i = 32 * tt + l31;
      float sg = SCb[i] + SCb[128 + i] + SCb[256 + i] + SCb[384 + i];
      float inv = 1.f / sg;
      #pragma unroll
      for (int reg = 0; reg < 16; ++reg) accS[tt][reg] *= inv;
    }
    #pragma unroll
    for (int tt = 0; tt < 4; ++tt)
      stageB64(R2s, accS[tt], 32 * tt + l31, mblk, h5, 1.f);    // attn[i][j] -> R2

    // vm = mag @ Wvm (mag still resident in R1 — no restage)
    {
      f32x16 accVM[4];
      #pragma unroll
      for (int tt = 0; tt < 4; ++tt) {
        float bv = bvm[l * 128 + 32 * tt + l31];
        #pragma unroll
        for (int reg = 0; reg < 16; ++reg) accVM[tt][reg] = bv;
      }
      gemmNW4(accVM, R1s, wvmP, mblk, l31, h5, lane);
      __syncthreads();                               // all mag reads done
      #pragma unroll
      for (int tt = 0; tt < 4; ++tt)
        stageB64(R1s, accVM[tt], 32 * tt + l31, mblk, h5, 1.f); // vmT[h][j] -> R1
      __syncthreads();                               // vm + attn ready
    }

    // new_mag^T = vm^T @ attn^T + mag^T  (accM: h=32w+ROWP, i=32tt+l31)
    f32x16 accM[4];
    #pragma unroll
    for (int tt = 0; tt < 4; ++tt) accM[tt] = magT[tt];
    gemmLL4(accM, R1s, R2s, mblk, l31, h5);

    // LayerNorm over h: sum over regs + h5 partner + 4 waves
    {
      #pragma unroll
      for (int tt = 0; tt < 4; ++tt) {
        float s = 0.f, q = 0.f;
        #pragma unroll
        for (int reg = 0; reg < 16; ++reg) { float v = accM[tt][reg]; s += v; q += v*v; }
        s += __shfl_xor(s, 32); q += __shfl_xor(q, 32);
        if (h5 == 0) { SCa[w * 128 + 32 * tt + l31] = s; SCb[w * 128 + 32 * tt + l31] = q; }
      }
      __syncthreads();
      #pragma unroll
      for (int reg = 0; reg < 16; ++reg) {
        float gv = ln_g[l * 128 + 32 * w + ROWP(reg)];
        float bv = ln_b[l * 128 + 32 * w + ROWP(reg)];
        #pragma unroll
        for (int tt = 0; tt < 4; ++tt) {
          int i = 32 * tt + l31;
          float s = SCa[i] + SCa[128 + i] + SCa[256 + i] + SCa[384 + i];
          float q = SCb[i] + SCb[128 + i] + SCb[256 + i] + SCb[384 + i];
          float mu = s * (1.f / 128.f);
          float var = q * (1.f / 128.f) - mu * mu;
          float inv = 1.f / sqrtf(var + 1e-5f);
          magT[tt][reg] = gv * ((accM[tt][reg] - mu) * inv) + bv;
        }
      }
    }
    #pragma unroll
    for (int tt = 0; tt < 4; ++tt)
      stageB64(R1s, phT[tt], 32 * tt + l31, mblk, h5, 1.f);     // ph[a][h] -> R1
    __syncthreads();

    // vp = ph @ Wvp (normal); staged as vpT[h][j]
    {
      f32x16 accV[4];
      #pragma unroll
      for (int tt = 0; tt < 4; ++tt) {
        float bv = bvp[l * 128 + 32 * tt + l31];
        #pragma unroll
        for (int reg = 0; reg < 16; ++reg) accV[tt][reg] = bv;
      }
      gemmNW4(accV, R1s, wvpP, mblk, l31, h5, lane);
      __syncthreads();                               // all ph reads done
      #pragma unroll
      for (int tt = 0; tt < 4; ++tt)
        stageB64(R1s, accV[tt], 32 * tt + l31, mblk, h5, 1.f);  // vpT[h][j] -> R1
      __syncthreads();
    }

    // new_ph^T = vp^T @ attn^T + ph^T
    f32x16 accP[4];
    #pragma unroll
    for (int tt = 0; tt < 4; ++tt) accP[tt] = phT[tt];
    gemmLL4(accP, R1s, R2s, mblk, l31, h5);
    #pragma unroll
    for (int tt = 0; tt < 4; ++tt) phT[tt] = accP[tt];
  } // layers

  // ---- real/imag -> RealProjection (transposed accR: hout=32w+ROWP, a=32tt+l31) ----
  f32x16 reT[4], imT[4];
  #pragma unroll
  for (int tt = 0; tt < 4; ++tt)
    #pragma unroll
    for (int reg = 0; reg < 16; ++reg) {
      float s_, c_;
      __sincosf(phT[tt][reg], &s_, &c_);
      reT[tt][reg] = magT[tt][reg] * c_;
      imT[tt][reg] = magT[tt][reg] * s_;
    }
  __syncthreads();
  #pragma unroll
  for (int tt = 0; tt < 4; ++tt) {
    stageB64(R1s, reT[tt], 32 * tt + l31, mblk, h5, 1.f);   // re[a][h] -> R1
    stageB64(R2s, imT[tt], 32 * tt + l31, mblk, h5, 1.f);   // im[a][h] -> R2
  }
  __syncthreads();
  f32x16 accR[4];
  #pragma unroll
  for (int reg = 0; reg < 16; ++reg) {
    float bv = rp_b[32 * w + ROWP(reg)];
    #pragma unroll
    for (int tt = 0; tt < 4; ++tt) accR[tt][reg] = bv;
  }
  gemmTW4(accR, wpre + (size_t)12 * 65536, R1s, w, 8, l31, h5, lane);  // rpA^T @ re^T
  gemmTW4(accR, wpre + (size_t)13 * 65536, R2s, w, 8, l31, h5, lane);  // rpB^T @ im^T

  // ---- pooling: column sum over atoms a (tt in-thread + l31 shfl) ----
  {
    float cs[16];
    #pragma unroll
    for (int reg = 0; reg < 16; ++reg) {
      float s = accR[0][reg] + accR[1][reg] + accR[2][reg] + accR[3][reg];
      s += __shfl_xor(s, 16); s += __shfl_xor(s, 8);
      s += __shfl_xor(s, 4);  s += __shfl_xor(s, 2); s += __shfl_xor(s, 1);
      cs[reg] = s;
    }
    if (l31 == 0) {
      #pragma unroll
      for (int reg = 0; reg < 16; ++reg) SCa[32 * w + ROWP(reg)] = cs[reg];
    }
  }
  __syncthreads();
  if (t < 128) {
    float acc = h1_b[t];
    for (int i = 0; i < 128; ++i) {
      float c = SCa[i];
      acc += c * (h1_W[(size_t)i * 128 + t] * (1.f / 128.f) +
                  h1_W[(size_t)(128 + i) * 128 + t]);
    }
    float hv = acc / (1.f + __expf(-acc));   // SiLU
    SCb[t] = hv * h2_W[t];
  }
  __syncthreads();
  if (t < 64) {
    float s2 = SCb[t] + SCb[64 + t];
    #pragma unroll
    for (int off = 32; off >= 1; off >>= 1) s2 += __shfl_xor(s2, off);
    if (t == 0) out[b] = s2 + h2_b[0];
  }
}

extern "C" void kernel_launch(void* const* d_in, const int* in_sizes, int n_in,
                              void* d_out, int out_size, void* d_ws, size_t ws_size,
                              hipStream_t stream) {
  const float* atom_types = (const float*)d_in[0];
  const float* coords     = (const float*)d_in[1];
  const int*   edge_index = (const int*)  d_in[2];
  const float* edge_attr  = (const float*)d_in[3];
  const float* emb_Wm = (const float*)d_in[4];
  const float* emb_bm = (const float*)d_in[5];
  const float* emb_Wp = (const float*)d_in[6];
  const float* emb_bp = (const float*)d_in[7];
  const float* Wq  = (const float*)d_in[8];
  const float* bq  = (const float*)d_in[9];
  const float* Wk  = (const float*)d_in[10];
  const float* bk  = (const float*)d_in[11];
  const float* Wvm = (const float*)d_in[12];
  const float* bvm = (const float*)d_in[13];
  const float* Wvp = (const float*)d_in[14];
  const float* bvp = (const float*)d_in[15];
  const float* We  = (const float*)d_in[16];
  const float* be  = (const float*)d_in[17];
  const float* dist_scale = (const float*)d_in[18];
  const float* ln_g = (const float*)d_in[19];
  const float* ln_b = (const float*)d_in[20];
  const float* rp_W = (const float*)d_in[21];
  const float* rp_b = (const float*)d_in[22];
  const float* h1_W = (const float*)d_in[23];
  const float* h1_b = (const float*)d_in[24];
  const float* h2_W = (const float*)d_in[25];
  const float* h2_b = (const float*)d_in[26];
  float* out = (float*)d_out;
  (void)bk;
  // workspace layout: 16 packed mats (16*131072 B) | u (512 f32) | W' (65536 f32)
  short* wpre   = (short*)d_ws;
  float* uArr   = (float*)((char*)d_ws + (size_t)16 * 131072);
  float* wprime = (float*)((char*)d_ws + (size_t)16 * 131072 + 2048);

  hipLaunchKernelGGL(prep0_kernel, dim3(16), dim3(256), 0, stream,
                     Wq, Wk, bq, wprime, uArr);
  hipLaunchKernelGGL(prep_kernel, dim3(64), dim3(512), 0, stream,
                     wprime, Wvm, Wvp, rp_W, emb_Wm, emb_Wp, wpre);
  hipLaunchKernelGGL(cpt_kernel, dim3(1024), dim3(256), 0, stream,
                     atom_types, coords, edge_index, edge_attr,
                     emb_bm, emb_bp,
                     bvm, bvp,
                     We, be, dist_scale, ln_g, ln_b,
                     rp_b, h1_W, h1_b, h2_W, h2_b,
                     (const short*)wpre, (const float*)uArr, out);
}

// Round 2
// 621.829 us; speedup vs baseline: 1.4903x; 1.2627x over previous
//
#include <hip/hip_runtime.h>
#include <math.h>

// ComplexPolarTransformerBeta — round 10: 8-wave (512-thread) blocks.
// Same 143KB LDS caps us at 1 block/CU, so instead get 2 waves/SIMD from a
// single 512-thread block: wave w owns m-block wm=w>>1 (32 rows) and HALF the
// tt column-tiles (ttb=2*(w&1), 2 tiles of 32). Per-wave accumulator state
// halves (magT/phT/accS etc 4->2 => ~180 live VGPRs), __launch_bounds__(512,2)
// caps the allocator at 256 so both waves fit a SIMD. All LDS layouts, barrier
// structure and the QK-fused algebra (scores = scale*M W' M^T + v) from round 9
// are unchanged; cross-wave reductions write the same 4x128 partial slots
// (wave pairs fill disjoint halves). Co-resident waves hide ds_read->MFMA and
// L2 weight-load latency that was fully exposed at 1 wave/SIMD.

typedef __attribute__((ext_vector_type(8)))  short s16x8;
typedef __attribute__((ext_vector_type(16))) float f32x16;

#define STR  136      // LDS row stride (shorts): 128 data + 8 pad
#define LOFS 17408    // lo-plane offset within a region (shorts)
#define MFMA(a, b, c) __builtin_amdgcn_mfma_f32_32x32x16_bf16(a, b, c, 0, 0, 0)
#define ROWP(reg) (((reg) & 3) + (((reg) >> 2) << 3) + (h5 << 2))

__device__ __forceinline__ unsigned short bfhi(float x) {
  unsigned u = __float_as_uint(x);
  return (unsigned short)((u + 0x7FFFu + ((u >> 16) & 1u)) >> 16);
}
__device__ __forceinline__ float bf2f(unsigned short h) {
  return __uint_as_float(((unsigned)h) << 16);
}

// Stage one C-layout tile into S[row][colbase + 8q + 4h5] as bf16 hi/lo (b64).
__device__ __forceinline__ void stageB64(short* SH, const f32x16& acc, int row,
                                         int colbase, int h5, float scl) {
  #pragma unroll
  for (int q = 0; q < 4; ++q) {
    int col = colbase + 8 * q + 4 * h5;
    float v0 = acc[4*q+0] * scl, v1 = acc[4*q+1] * scl;
    float v2 = acc[4*q+2] * scl, v3 = acc[4*q+3] * scl;
    unsigned short h0 = bfhi(v0), h1 = bfhi(v1), h2 = bfhi(v2), h3 = bfhi(v3);
    *(short4*)(SH + row * STR + col) = make_short4((short)h0,(short)h1,(short)h2,(short)h3);
    *(short4*)(SH + LOFS + row * STR + col) =
        make_short4((short)bfhi(v0 - bf2f(h0)), (short)bfhi(v1 - bf2f(h1)),
                    (short)bfhi(v2 - bf2f(h2)), (short)bfhi(v3 - bf2f(h3)));
  }
}

// acc[j] += Wfrag(m-tile)^ * B(LDS rows 32*(ttb+j)+l31).  D[m=frag][n=LDS-row]
__device__ __forceinline__ void gemmTW2(f32x16* acc, const short* W, const short* BH,
                                        int mtile, int kbN, int ttb, int l31, int h5,
                                        int lane) {
  #pragma unroll 1
  for (int kb = 0; kb < kbN; ++kb) {
    const short* wp = W + (((mtile * 8 + kb) * 64 + lane) * 8);
    s16x8 ah = *(const s16x8*)wp;
    s16x8 al = *(const s16x8*)(wp + 32768);
    int k0 = kb * 16 + 8 * h5;
    #pragma unroll
    for (int j = 0; j < 2; ++j) {
      int brow = 32 * (ttb + j) + l31;
      s16x8 bh = *(const s16x8*)(BH + brow * STR + k0);
      s16x8 bl = *(const s16x8*)(BH + LOFS + brow * STR + k0);
      acc[j] = MFMA(ah, bh, acc[j]);
      acc[j] = MFMA(ah, bl, acc[j]);
      acc[j] = MFMA(al, bh, acc[j]);
    }
  }
}

// acc[j] += A(LDS rows mblk+l31) * Wfrag(n-tile=ttb+j).  D[m=LDS-row][n=frag]
__device__ __forceinline__ void gemmNW2(f32x16* acc, const short* AH, const short* W,
                                        int mblk, int ttb, int l31, int h5, int lane) {
  int arow = mblk + l31;
  #pragma unroll 1
  for (int kb = 0; kb < 8; ++kb) {
    int k0 = kb * 16 + 8 * h5;
    s16x8 ah = *(const s16x8*)(AH + arow * STR + k0);
    s16x8 al = *(const s16x8*)(AH + LOFS + arow * STR + k0);
    #pragma unroll
    for (int j = 0; j < 2; ++j) {
      const short* wp = W + ((((ttb + j) * 8 + kb) * 64 + lane) * 8);
      s16x8 bh = *(const s16x8*)wp;
      s16x8 bl = *(const s16x8*)(wp + 32768);
      acc[j] = MFMA(ah, bh, acc[j]);
      acc[j] = MFMA(ah, bl, acc[j]);
      acc[j] = MFMA(al, bh, acc[j]);
    }
  }
}

// acc[j] += A(LDS rows mblk+l31) * B(LDS rows 32*(ttb+j)+l31)^T.
__device__ __forceinline__ void gemmLL2(f32x16* acc, const short* AH, const short* BH,
                                        int mblk, int ttb, int l31, int h5) {
  int arow = mblk + l31;
  #pragma unroll 1
  for (int kb = 0; kb < 8; ++kb) {
    int k0 = kb * 16 + 8 * h5;
    s16x8 ah = *(const s16x8*)(AH + arow * STR + k0);
    s16x8 al = *(const s16x8*)(AH + LOFS + arow * STR + k0);
    #pragma unroll
    for (int j = 0; j < 2; ++j) {
      int brow = 32 * (ttb + j) + l31;
      s16x8 bh = *(const s16x8*)(BH + brow * STR + k0);
      s16x8 bl = *(const s16x8*)(BH + LOFS + brow * STR + k0);
      acc[j] = MFMA(ah, bh, acc[j]);
      acc[j] = MFMA(ah, bl, acc[j]);
      acc[j] = MFMA(al, bh, acc[j]);
    }
  }
}

// ---------------- prep0: W'[l] = Wq[l] @ Wk[l]^T (fp32), u[l] = scale*Wk[l]@bq[l] ----
__global__ __launch_bounds__(256)
void prep0_kernel(const float* __restrict__ Wq, const float* __restrict__ Wk,
                  const float* __restrict__ bq,
                  float* __restrict__ wprime, float* __restrict__ u) {
  __shared__ float WkS[128 * 129];
  __shared__ float WqS[32 * 129];
  int l = blockIdx.x >> 2, ablk = blockIdx.x & 3;
  int t = threadIdx.x;
  const float* wk = Wk + (size_t)l * 16384;
  const float* wq = Wq + (size_t)l * 16384 + ablk * 32 * 128;
  for (int idx = t; idx < 16384; idx += 256)
    WkS[(idx >> 7) * 129 + (idx & 127)] = wk[idx];
  for (int idx = t; idx < 4096; idx += 256)
    WqS[(idx >> 7) * 129 + (idx & 127)] = wq[idx];
  __syncthreads();
  int a = t >> 3, bs = t & 7;
  float acc[16];
  #pragma unroll
  for (int j = 0; j < 16; ++j) acc[j] = 0.f;
  for (int c = 0; c < 128; ++c) {
    float qa = WqS[a * 129 + c];
    #pragma unroll
    for (int j = 0; j < 16; ++j) acc[j] += qa * WkS[(8 * j + bs) * 129 + c];
  }
  float* dst = wprime + ((size_t)l * 128 + ablk * 32 + a) * 128;
  #pragma unroll
  for (int j = 0; j < 16; ++j) dst[8 * j + bs] = acc[j];
  if (ablk == 0 && t < 128) {
    float s = 0.f;
    const float* bql = bq + l * 128;
    for (int c = 0; c < 128; ++c) s += WkS[t * 129 + c] * bql[c];
    u[l * 128 + t] = 0.08838834764831845f * s;
  }
}

// ---------------- weight packing: fp32 [k][h] -> frag-ordered bf16 hi/lo ----------
// mids: 0-3 W', 4-7 Wvm, 8-11 Wvp, 12-13 rp_W halves, 14-15 emb.
__global__ __launch_bounds__(512)
void prep_kernel(const float* __restrict__ wprime,
                 const float* __restrict__ Wvm, const float* __restrict__ Wvp,
                 const float* __restrict__ rp_W,
                 const float* __restrict__ emb_Wm, const float* __restrict__ emb_Wp,
                 short* __restrict__ ws) {
  int mid = blockIdx.x >> 2, hblk = blockIdx.x & 3;
  int kb = threadIdx.x >> 6, lane = threadIdx.x & 63;
  const float* src;
  int krows = 128;
  if (mid < 4)        src = wprime + (size_t)mid * 16384;
  else if (mid < 8)   src = Wvm + (size_t)(mid - 4) * 16384;
  else if (mid < 12)  src = Wvp + (size_t)(mid - 8) * 16384;
  else if (mid == 12) src = rp_W;
  else if (mid == 13) src = rp_W + 16384;
  else if (mid == 14) { src = emb_Wm; krows = 19; }
  else                { src = emb_Wp; krows = 19; }
  int h = hblk * 32 + (lane & 31);
  int kbase = kb * 16 + ((lane >> 5) << 3);
  s16x8 H, L;
  #pragma unroll
  for (int j = 0; j < 8; ++j) {
    int k = kbase + j;
    float v = (k < krows) ? src[(size_t)k * 128 + h] : 0.f;
    unsigned short hi = bfhi(v);
    H[j] = (short)hi;
    L[j] = (short)bfhi(v - bf2f(hi));
  }
  short* dst = ws + (size_t)mid * 65536 + ((hblk * 8 + kb) * 64 + lane) * 8;
  *(s16x8*)dst = H;
  *(s16x8*)(dst + 32768) = L;
}

// ---------------- main kernel ----------------
__global__ __launch_bounds__(512, 2)
void cpt_kernel(const float* __restrict__ atom_types,
                const float* __restrict__ coords,
                const int*   __restrict__ edge_index,
                const float* __restrict__ edge_attr,
                const float* __restrict__ emb_bm, const float* __restrict__ emb_bp,
                const float* __restrict__ bvm, const float* __restrict__ bvp,
                const float* __restrict__ We,  const float* __restrict__ be,
                const float* __restrict__ dist_scale,
                const float* __restrict__ ln_g, const float* __restrict__ ln_b,
                const float* __restrict__ rp_b,
                const float* __restrict__ h1_W, const float* __restrict__ h1_b,
                const float* __restrict__ h2_W, const float* __restrict__ h2_b,
                const short* __restrict__ wpre, const float* __restrict__ uArr,
                float* __restrict__ out)
{
  __shared__ __align__(16) short R1s[34816];
  __shared__ __align__(16) short R2s[34816];
  __shared__ float SCa[512];
  __shared__ float SCb[512];

  const int t = threadIdx.x, b = blockIdx.x;
  const int w = t >> 6, lane = t & 63, l31 = lane & 31, h5 = lane >> 5;
  const int wm = w >> 1, ttb = (w & 1) << 1;
  const int mblk = wm << 5;
  const float scale = 0.08838834764831845f;  // 1/sqrt(128)

  // ---- stage x (atom_types||coords, k padded to 32) into R1 as bf16 hi/lo ----
  if (t < 128) {
    const float* xr = atom_types + ((size_t)b * 128 + t) * 16;
    const float* cr = coords + ((size_t)b * 128 + t) * 3;
    float xv[19];
    float4 a0 = *(const float4*)xr,       a1 = *(const float4*)(xr + 4);
    float4 a2 = *(const float4*)(xr + 8), a3 = *(const float4*)(xr + 12);
    xv[0]=a0.x; xv[1]=a0.y; xv[2]=a0.z; xv[3]=a0.w;
    xv[4]=a1.x; xv[5]=a1.y; xv[6]=a1.z; xv[7]=a1.w;
    xv[8]=a2.x; xv[9]=a2.y; xv[10]=a2.z; xv[11]=a2.w;
    xv[12]=a3.x; xv[13]=a3.y; xv[14]=a3.z; xv[15]=a3.w;
    xv[16]=cr[0]; xv[17]=cr[1]; xv[18]=cr[2];
    #pragma unroll
    for (int k = 0; k < 32; ++k) {
      float v = (k < 19) ? xv[k] : 0.f;
      unsigned short hh = bfhi(v);
      R1s[t * STR + k] = (short)hh;
      R1s[LOFS + t * STR + k] = (short)bfhi(v - bf2f(hh));
    }
  }
  __syncthreads();

  // ---- embedding via MFMA: magT/phT (TRANSPOSED: h=32wm+ROWP(reg), a=32(ttb+j)+l31) ----
  f32x16 magT[2], phT[2];
  {
    #pragma unroll
    for (int reg = 0; reg < 16; ++reg) {
      float bm = emb_bm[32 * wm + ROWP(reg)];
      float bp = emb_bp[32 * wm + ROWP(reg)];
      #pragma unroll
      for (int j = 0; j < 2; ++j) { magT[j][reg] = bm; phT[j][reg] = bp; }
    }
    gemmTW2(magT, wpre + (size_t)14 * 65536, R1s, wm, 2, ttb, l31, h5, lane);
    gemmTW2(phT,  wpre + (size_t)15 * 65536, R1s, wm, 2, ttb, l31, h5, lane);
  }

  // ---- layers ----
  for (int l = 0; l < 4; ++l) {
    const short* wpP  = wpre + (size_t)l * 65536;        // W' pack
    const short* wvmP = wpre + (size_t)(4 + l) * 65536;
    const short* wvpP = wpre + (size_t)(8 + l) * 65536;
    float* Bf = (float*)R2s;                             // 128x128 bias, [j][i]

    __syncthreads();                                 // prior layer readers done
    #pragma unroll
    for (int j = 0; j < 2; ++j)
      stageB64(R1s, magT[j], 32 * (ttb + j) + l31, mblk, h5, 1.f);  // mag[a][h] -> R1
    {
      float4 z4 = make_float4(0.f, 0.f, 0.f, 0.f);
      #pragma unroll
      for (int k = 0; k < 8; ++k) *(float4*)(Bf + (t + 512 * k) * 4) = z4;
    }
    // v partials: v_a = sum_h mag[a][h] * u[h]  (this wave's 32-h block)
    {
      float ur[16];
      #pragma unroll
      for (int reg = 0; reg < 16; ++reg) ur[reg] = uArr[l * 128 + 32 * wm + ROWP(reg)];
      #pragma unroll
      for (int j = 0; j < 2; ++j) {
        float p = 0.f;
        #pragma unroll
        for (int reg = 0; reg < 16; ++reg) p += magT[j][reg] * ur[reg];
        p += __shfl_xor(p, 32);
        if (h5 == 0) SCa[wm * 128 + 32 * (ttb + j) + l31] = p;
      }
    }
    __syncthreads();                                 // mag/Bf-zero/v ready

    // edge bias scatter: Bf[j][i] += bval
    {
      float w0 = We[l*4], w1 = We[l*4+1], w2 = We[l*4+2], w3 = We[l*4+3];
      float bel = be[l], dsl = dist_scale[l];
      #pragma unroll
      for (int k = 0; k < 2; ++k) {
        int e = t + 512 * k;
        int e0 = edge_index[(size_t)b * 2048 + e];
        int e1 = edge_index[(size_t)b * 2048 + 1024 + e];
        float4 ea = *(const float4*)(edge_attr + ((size_t)b * 1024 + e) * 4);
        float bv = ea.x*w0 + ea.y*w1 + ea.z*w2 + ea.w*w3 + bel + dsl*ea.x;
        atomicAdd(&Bf[e1 * 128 + e0], bv);
      }
    }

    // T = mag @ W'  (accT: m=b'=32wm+ROWP, n=i=32(ttb+j)+l31); mag stays in R1
    f32x16 accT[2];
    #pragma unroll
    for (int j = 0; j < 2; ++j)
      #pragma unroll
      for (int reg = 0; reg < 16; ++reg) accT[j][reg] = 0.f;
    gemmTW2(accT, wpP, R1s, wm, 8, ttb, l31, h5, lane);
    __syncthreads();                                 // atomics visible

    // accS init = bias[i][j] + v_j  (m=j=32wm+ROWP, n=i=32(ttb+j)+l31)
    f32x16 accS[2];
    {
      float vj[16];
      #pragma unroll
      for (int reg = 0; reg < 16; ++reg) {
        int jj = 32 * wm + ROWP(reg);
        vj[reg] = SCa[jj] + SCa[128 + jj] + SCa[256 + jj] + SCa[384 + jj];
      }
      #pragma unroll
      for (int j = 0; j < 2; ++j) {
        #pragma unroll
        for (int reg = 0; reg < 16; ++reg)
          accS[j][reg] = Bf[(32 * wm + ROWP(reg)) * 128 + 32 * (ttb + j) + l31] + vj[reg];
      }
    }
    __syncthreads();                                 // Bf reads done
    #pragma unroll
    for (int j = 0; j < 2; ++j)
      stageB64(R2s, accT[j], 32 * (ttb + j) + l31, mblk, h5, scale);  // Ts[i][b'] -> R2
    __syncthreads();                                 // Ts ready

    // scoresT[j][i] = mag @ Ts^T + bias + v
    gemmLL2(accS, R1s, R2s, mblk, ttb, l31, h5);

    // softmax over j (regs + h5 partner + 4 m-blocks via SCa/SCb)
    #pragma unroll
    for (int j = 0; j < 2; ++j) {
      float m = accS[j][0];
      #pragma unroll
      for (int reg = 1; reg < 16; ++reg) m = fmaxf(m, accS[j][reg]);
      m = fmaxf(m, __shfl_xor(m, 32));
      if (h5 == 0) SCa[wm * 128 + 32 * (ttb + j) + l31] = m;
    }
    __syncthreads();
    #pragma unroll
    for (int j = 0; j < 2; ++j) {
      int i = 32 * (ttb + j) + l31;
      float mg = fmaxf(fmaxf(SCa[i], SCa[128 + i]), fmaxf(SCa[256 + i], SCa[384 + i]));
      float s = 0.f;
      #pragma unroll
      for (int reg = 0; reg < 16; ++reg) {
        float e = __expf(accS[j][reg] - mg);
        accS[j][reg] = e; s += e;
      }
      s += __shfl_xor(s, 32);
      if (h5 == 0) SCb[wm * 128 + i] = s;
    }
    __syncthreads();
    #pragma unroll
    for (int j = 0; j < 2; ++j) {
      int i = 32 * (ttb + j) + l31;
      float sg = SCb[i] + SCb[128 + i] + SCb[256 + i] + SCb[384 + i];
      float inv = 1.f / sg;
      #pragma unroll
      for (int reg = 0; reg < 16; ++reg) accS[j][reg] *= inv;
    }
    #pragma unroll
    for (int j = 0; j < 2; ++j)
      stageB64(R2s, accS[j], 32 * (ttb + j) + l31, mblk, h5, 1.f);  // attn[i][j] -> R2

    // vm = mag @ Wvm (mag still resident in R1 — no restage)
    {
      f32x16 accVM[2];
      #pragma unroll
      for (int j = 0; j < 2; ++j) {
        float bv = bvm[l * 128 + 32 * (ttb + j) + l31];
        #pragma unroll
        for (int reg = 0; reg < 16; ++reg) accVM[j][reg] = bv;
      }
      gemmNW2(accVM, R1s, wvmP, mblk, ttb, l31, h5, lane);
      __syncthreads();                               // all mag reads done
      #pragma unroll
      for (int j = 0; j < 2; ++j)
        stageB64(R1s, accVM[j], 32 * (ttb + j) + l31, mblk, h5, 1.f); // vmT[h][j] -> R1
      __syncthreads();                               // vm + attn ready
    }

    // new_mag^T = vm^T @ attn^T + mag^T  (accM: h=32wm+ROWP, i=32(ttb+j)+l31)
    f32x16 accM[2];
    #pragma unroll
    for (int j = 0; j < 2; ++j) accM[j] = magT[j];
    gemmLL2(accM, R1s, R2s, mblk, ttb, l31, h5);

    // LayerNorm over h: sum over regs + h5 partner + 4 m-blocks
    {
      #pragma unroll
      for (int j = 0; j < 2; ++j) {
        float s = 0.f, q = 0.f;
        #pragma unroll
        for (int reg = 0; reg < 16; ++reg) { float v = accM[j][reg]; s += v; q += v*v; }
        s += __shfl_xor(s, 32); q += __shfl_xor(q, 32);
        if (h5 == 0) {
          SCa[wm * 128 + 32 * (ttb + j) + l31] = s;
          SCb[wm * 128 + 32 * (ttb + j) + l31] = q;
        }
      }
      __syncthreads();
      #pragma unroll
      for (int reg = 0; reg < 16; ++reg) {
        float gv = ln_g[l * 128 + 32 * wm + ROWP(reg)];
        float bv = ln_b[l * 128 + 32 * wm + ROWP(reg)];
        #pragma unroll
        for (int j = 0; j < 2; ++j) {
          int i = 32 * (ttb + j) + l31;
          float s = SCa[i] + SCa[128 + i] + SCa[256 + i] + SCa[384 + i];
          float q = SCb[i] + SCb[128 + i] + SCb[256 + i] + SCb[384 + i];
          float mu = s * (1.f / 128.f);
          float var = q * (1.f / 128.f) - mu * mu;
          float inv = 1.f / sqrtf(var + 1e-5f);
          magT[j][reg] = gv * ((accM[j][reg] - mu) * inv) + bv;
        }
      }
    }
    #pragma unroll
    for (int j = 0; j < 2; ++j)
      stageB64(R1s, phT[j], 32 * (ttb + j) + l31, mblk, h5, 1.f);   // ph[a][h] -> R1
    __syncthreads();

    // vp = ph @ Wvp (normal); staged as vpT[h][j]
    {
      f32x16 accV[2];
      #pragma unroll
      for (int j = 0; j < 2; ++j) {
        float bv = bvp[l * 128 + 32 * (ttb + j) + l31];
        #pragma unroll
        for (int reg = 0; reg < 16; ++reg) accV[j][reg] = bv;
      }
      gemmNW2(accV, R1s, wvpP, mblk, ttb, l31, h5, lane);
      __syncthreads();                               // all ph reads done
      #pragma unroll
      for (int j = 0; j < 2; ++j)
        stageB64(R1s, accV[j], 32 * (ttb + j) + l31, mblk, h5, 1.f); // vpT[h][j] -> R1
      __syncthreads();
    }

    // new_ph^T = vp^T @ attn^T + ph^T
    f32x16 accP[2];
    #pragma unroll
    for (int j = 0; j < 2; ++j) accP[j] = phT[j];
    gemmLL2(accP, R1s, R2s, mblk, ttb, l31, h5);
    #pragma unroll
    for (int j = 0; j < 2; ++j) phT[j] = accP[j];
  } // layers

  // ---- real/imag -> RealProjection (transposed accR: hout=32wm+ROWP, a=32(ttb+j)+l31) ----
  f32x16 reT[2], imT[2];
  #pragma unroll
  for (int j = 0; j < 2; ++j)
    #pragma unroll
    for (int reg = 0; reg < 16; ++reg) {
      float s_, c_;
      __sincosf(phT[j][reg], &s_, &c_);
      reT[j][reg] = magT[j][reg] * c_;
      imT[j][reg] = magT[j][reg] * s_;
    }
  __syncthreads();
  #pragma unroll
  for (int j = 0; j < 2; ++j) {
    stageB64(R1s, reT[j], 32 * (ttb + j) + l31, mblk, h5, 1.f);   // re[a][h] -> R1
    stageB64(R2s, imT[j], 32 * (ttb + j) + l31, mblk, h5, 1.f);   // im[a][h] -> R2
  }
  __syncthreads();
  f32x16 accR[2];
  #pragma unroll
  for (int reg = 0; reg < 16; ++reg) {
    float bv = rp_b[32 * wm + ROWP(reg)];
    #pragma unroll
    for (int j = 0; j < 2; ++j) accR[j][reg] = bv;
  }
  gemmTW2(accR, wpre + (size_t)12 * 65536, R1s, wm, 8, ttb, l31, h5, lane);  // rpA^T @ re^T
  gemmTW2(accR, wpre + (size_t)13 * 65536, R2s, wm, 8, ttb, l31, h5, lane);  // rpB^T @ im^T

  // ---- pooling: column sum over atoms a (j in-thread + l31 shfl + partner wave) ----
  {
    float cs[16];
    #pragma unroll
    for (int reg = 0; reg < 16; ++reg) {
      float s = accR[0][reg] + accR[1][reg];
      s += __shfl_xor(s, 16); s += __shfl_xor(s, 8);
      s += __shfl_xor(s, 4);  s += __shfl_xor(s, 2); s += __shfl_xor(s, 1);
      cs[reg] = s;
    }
    if (l31 == 0) {
      #pragma unroll
      for (int reg = 0; reg < 16; ++reg)
        SCa[(w & 1) * 128 + 32 * wm + ROWP(reg)] = cs[reg];
    }
  }
  __syncthreads();
  if (t < 128) {
    float acc = h1_b[t];
    for (int i = 0; i < 128; ++i) {
      float c = SCa[i] + SCa[128 + i];
      acc += c * (h1_W[(size_t)i * 128 + t] * (1.f / 128.f) +
                  h1_W[(size_t)(128 + i) * 128 + t]);
    }
    float hv = acc / (1.f + __expf(-acc));   // SiLU
    SCb[t] = hv * h2_W[t];
  }
  __syncthreads();
  if (t < 64) {
    float s2 = SCb[t] + SCb[64 + t];
    #pragma unroll
    for (int off = 32; off >= 1; off >>= 1) s2 += __shfl_xor(s2, off);
    if (t == 0) out[b] = s2 + h2_b[0];
  }
}

extern "C" void kernel_launch(void* const* d_in, const int* in_sizes, int n_in,
                              void* d_out, int out_size, void* d_ws, size_t ws_size,
                              hipStream_t stream) {
  const float* atom_types = (const float*)d_in[0];
  const float* coords     = (const float*)d_in[1];
  const int*   edge_index = (const int*)  d_in[2];
  const float* edge_attr  = (const float*)d_in[3];
  const float* emb_Wm = (const float*)d_in[4];
  const float* emb_bm = (const float*)d_in[5];
  const float* emb_Wp = (const float*)d_in[6];
  const float* emb_bp = (const float*)d_in[7];
  const float* Wq  = (const float*)d_in[8];
  const float* bq  = (const float*)d_in[9];
  const float* Wk  = (const float*)d_in[10];
  const float* bk  = (const float*)d_in[11];
  const float* Wvm = (const float*)d_in[12];
  const float* bvm = (const float*)d_in[13];
  const float* Wvp = (const float*)d_in[14];
  const float* bvp = (const float*)d_in[15];
  const float* We  = (const float*)d_in[16];
  const float* be  = (const float*)d_in[17];
  const float* dist_scale = (const float*)d_in[18];
  const float* ln_g = (const float*)d_in[19];
  const float* ln_b = (const float*)d_in[20];
  const float* rp_W = (const float*)d_in[21];
  const float* rp_b = (const float*)d_in[22];
  const float* h1_W = (const float*)d_in[23];
  const float* h1_b = (const float*)d_in[24];
  const float* h2_W = (const float*)d_in[25];
  const float* h2_b = (const float*)d_in[26];
  float* out = (float*)d_out;
  (void)bk;
  // workspace layout: 16 packed mats (16*131072 B) | u (512 f32) | W' (65536 f32)
  short* wpre   = (short*)d_ws;
  float* uArr   = (float*)((char*)d_ws + (size_t)16 * 131072);
  float* wprime = (float*)((char*)d_ws + (size_t)16 * 131072 + 2048);

  hipLaunchKernelGGL(prep0_kernel, dim3(16), dim3(256), 0, stream,
                     Wq, Wk, bq, wprime, uArr);
  hipLaunchKernelGGL(prep_kernel, dim3(64), dim3(512), 0, stream,
                     wprime, Wvm, Wvp, rp_W, emb_Wm, emb_Wp, wpre);
  hipLaunchKernelGGL(cpt_kernel, dim3(1024), dim3(512), 0, stream,
                     atom_types, coords, edge_index, edge_attr,
                     emb_bm, emb_bp,
                     bvm, bvp,
                     We, be, dist_scale, ln_g, ln_b,
                     rp_b, h1_W, h1_b, h2_W, h2_b,
                     (const short*)wpre, (const float*)uArr, out);
}